// Round 1
// 118.389 us; speedup vs baseline: 1.0533x; 1.0533x over previous
//
#include <hip/hip_runtime.h>
#include <hip/hip_bf16.h>

// BlurredNoise via MFMA implicit GEMM, round 9 = round 8 with 2 waves/SIMD.
// R8 diagnosis: 1024 blocks x 1 wave = exactly 1 wave/SIMD (Occupancy 9.8%),
// MfmaUtil 17% / VALUBusy 7% -> ~76% exposed latency, no TLP to hide L2-hit
// B refills (~200cy) or LDS A-read latency (~120cy) in the W<=3 tail (117 of
// 169 steps). Fix: halve the per-block t-tile (mt 4->2, 32 t/block), double
// the grid to 2048 -> 8 waves/CU = 2/SIMD. k-loop schedule, LDS layout,
// staging and vmcnt structure unchanged; acc 128->64 VGPR so 2 waves fit
// (guarded by __launch_bounds__(64,2)).
// out[bc][F][t] = scale[F] * sum_j x[bc][t+j] * k[F][j]

#define KS      5000
#define IN_SEQ  9095
#define T_OUT   4096
#define NBC     16
#define NF      128
#define NSTEP   157
#define SWZSTEP 176               // padded per-tile step stride
#define CSTRIDE 1056              // bytes; /4 = 264 == 8 mod 32 -> uniform banks
#define XBUF    (4*CSTRIDE)       // 4224 B per parity buffer
#define XPS     9344              // padded x row stride (floats), front pad 32
#define SWZ_BYTES (8*SWZSTEP*512*2)   // 1,441,792
#define MT      2                 // m-tiles per block (32 output t)

typedef __attribute__((ext_vector_type(8))) short v8s;
typedef __attribute__((ext_vector_type(4))) float v4f;

__device__ __forceinline__ unsigned short f2b(float v) {
  union { __hip_bfloat16 h; unsigned short u; } cv;
  cv.h = __float2bfloat16(v);   // RNE
  return cv.u;
}

// ---- fused pre-kernel: (a) filters -> B-frag bf16; (b) zero-padded x copy ----
__global__ void build_pre(const float* __restrict__ filt,
                          const float* __restrict__ noise,
                          unsigned short* __restrict__ swz,
                          float* __restrict__ xpad) {
  const int b = blockIdx.x;
  if (b < 314) {                       // swz job: thread -> 8 consecutive shorts
    const int i = b * 256 + threadIdx.x;
    if (i >= 8 * NSTEP * 64) return;
    const int n  = i & 15;
    const int q  = (i >> 4) & 3;
    const int sb = i >> 6;
    const int ft = sb / NSTEP;
    const int s  = sb - ft * NSTEP;
    const int jg0 = KS - 32 * (s + 1) + 8 * q;
    const float* row = filt + (size_t)(ft * 16 + n) * KS;
    unsigned short o[8];
    #pragma unroll
    for (int j = 0; j < 8; ++j) {
      int jg = jg0 + j;
      int jc = jg < 0 ? 0 : jg;          // clamp ADDRESS, select VALUE
      float v = (jg >= 0) ? row[jc] : 0.0f;
      o[j] = f2b(v);
    }
    *(uint4*)(swz + (((size_t)(ft * SWZSTEP + s)) << 9) + (q << 7) + (n << 3)) = *(uint4*)o;
  } else {                             // xpad job: 16 x XPS, zeros outside
    const int i = (b - 314) * 256 + threadIdx.x;
    if (i >= NBC * XPS) return;
    const int r = i / XPS;
    const int pcol = i - r * XPS;
    const int lg = pcol - 32;
    xpad[i] = (lg >= 0 && lg < IN_SEQ) ? noise[r * IN_SEQ + lg] : 0.0f;
  }
}

// ---- one constant-width segment of the k-loop ----
// W: live tiles (n in [8-W,8)); U: steps/group; NG: groups; SB: first step;
// D: B-prefetch depth (U % D == 0). xb: LDS base (NO restrict — stage_write
// stores and A-reads load through the same provenance, order preserved).
template<int W, int U, int NG, int SB, int D>
__device__ __forceinline__ void run_seg(
    const char* __restrict__ bb, const float* __restrict__ xn,
    char* xb, int xrd_off, int t0, int lane, v4f (&acc)[MT][8])
{
  v8s breg[D][W];
  v8s areg[2][MT];
  float4 xr[3];
  const char* xrd = xb + xrd_off;      // may-alias xb: ds ordering preserved

  const char* sp[W];
  #pragma unroll
  for (int w = 0; w < W; ++w)
    sp[w] = bb + (((size_t)((8 - W + w) * SWZSTEP + SB)) << 10);

  auto stage_load = [&](int gg) {      // unconditional, aligned (padded buffer)
    const int g0 = t0 + KS - 32 * (SB + (gg + 1) * U);
    #pragma unroll
    for (int ii = 0; ii < 3; ++ii)
      xr[ii] = *(const float4*)(xn + (g0 + 8 * lane + 4 * ii));
  };
  auto stage_write = [&](int parity) { // xr -> 4 shifted bf16 LDS copies
    const float* f = (const float*)xr;
    unsigned u6[6];
    #pragma unroll
    for (int j = 0; j < 6; ++j)
      u6[j] = (unsigned)f2b(f[2 * j]) | ((unsigned)f2b(f[2 * j + 1]) << 16);
    auto AL = [](unsigned hi, unsigned lo) { return (lo >> 16) | (hi << 16); };
    char* buf = xb + parity * XBUF + 16 * lane;
    uint4 w0 = {u6[0], u6[1], u6[2], u6[3]};
    uint4 w1 = {AL(u6[1],u6[0]), AL(u6[2],u6[1]), AL(u6[3],u6[2]), AL(u6[4],u6[3])};
    uint4 w2 = {u6[1], u6[2], u6[3], u6[4]};
    uint4 w3 = {AL(u6[2],u6[1]), AL(u6[3],u6[2]), AL(u6[4],u6[3]), AL(u6[5],u6[4])};
    *(uint4*)(buf + 0 * CSTRIDE) = w0;
    *(uint4*)(buf + 1 * CSTRIDE) = w1;
    *(uint4*)(buf + 2 * CSTRIDE) = w2;
    *(uint4*)(buf + 3 * CSTRIDE) = w3;
  };
  auto read_A = [&](const char* p, v8s (&dst)[MT]) {
    #pragma unroll
    for (int mt = 0; mt < MT; ++mt) {
      v8s a;
      *(uint2*)&a       = *(const uint2*)(p + 32 * mt);
      *((uint2*)&a + 1) = *(const uint2*)(p + 32 * mt + 8);
      dst[mt] = a;
    }
  };

  // prologue: B depth-D, x group0 staged + group1 loaded, A step SB
  #pragma unroll
  for (int d = 0; d < D; ++d)
    #pragma unroll
    for (int w = 0; w < W; ++w)
      breg[d][w] = *(const v8s*)(sp[w] + (d << 10));
  stage_load(0);
  stage_write(0);
  stage_load(NG > 1 ? 1 : 0);
  read_A(xrd + 64 * (U - 1), areg[0]);

  #pragma unroll 1
  for (int g = 0; g < NG; ++g) {
    #pragma unroll
    for (int i = 0; i < U; ++i) {
      if (i == 1) stage_write((g + 1) & 1);   // garbage parity-write if g+1==NG (unread)
      if (i == 2) { int gg = g + 2; gg = gg > NG - 1 ? NG - 1 : gg; stage_load(gg); }
      // A prefetch for next step
      {
        const char* pn;
        if (i + 1 < U) {
          pn = xrd + (g & 1) * XBUF + 64 * (U - 2 - i);
        } else {
          int gn = (g + 1 < NG) ? (g + 1) : g;
          pn = xrd + (gn & 1) * XBUF + 64 * (U - 1);
        }
        read_A(pn, areg[(i + 1) & 1]);
      }
      // MFMA: use B slot i%D (loaded D steps ago), then refill same slot
      #pragma unroll
      for (int w = 0; w < W; ++w)
        #pragma unroll
        for (int mt = 0; mt < MT; ++mt)
          acc[mt][8 - W + w] = __builtin_amdgcn_mfma_f32_16x16x32_bf16(
              areg[i & 1][mt], breg[i % D][w], acc[mt][8 - W + w], 0, 0, 0);
      #pragma unroll
      for (int w = 0; w < W; ++w)
        breg[i % D][w] = *(const v8s*)(sp[w] + ((i + D) << 10));
    }
    #pragma unroll
    for (int w = 0; w < W; ++w) sp[w] += (U << 10);
  }
}

// ---- main kernel: 2048 blocks x 64 threads, identical waves, barrier-free ----
__global__ __launch_bounds__(64, 2) void blur_mfma(
    const float* __restrict__ xpad,
    const unsigned short* __restrict__ swz,
    const float* __restrict__ scale,
    float* __restrict__ out)
{
  __shared__ __align__(16) char xb[2 * XBUF];
  const int lane = threadIdx.x;
  const int b  = blockIdx.x;
  const int bc = b >> 7;                 // 16 bc, 128 t-chunks each
  const int t0 = (b & 127) << 5;         // 32 output t per block
  const int m = lane & 15, q = lane >> 4, c = m & 3;
  const float* __restrict__ xn = xpad + (size_t)bc * XPS + 32;  // logical origin
  const char* bb = (const char*)swz + 16 * lane;
  const int xrd_off = c * CSTRIDE + 8 * (m >> 2) + 16 * q;

  v4f acc[MT][8];
  const v4f vz = {0.f, 0.f, 0.f, 0.f};
  #pragma unroll
  for (int mt = 0; mt < MT; ++mt)
    #pragma unroll
    for (int n = 0; n < 8; ++n) acc[mt][n] = vz;

  // segments: <W, U, NG, SB, D>; S' = {8,12,16,28,40,64,100,157}
  run_seg<8,  8, 1,   0,  2>(bb, xn, xb, xrd_off, t0, lane, acc);
  run_seg<7,  4, 1,   8,  2>(bb, xn, xb, xrd_off, t0, lane, acc);
  run_seg<6,  4, 1,  12,  2>(bb, xn, xb, xrd_off, t0, lane, acc);
  run_seg<5, 12, 1,  16,  3>(bb, xn, xb, xrd_off, t0, lane, acc);
  run_seg<4, 12, 1,  28,  4>(bb, xn, xb, xrd_off, t0, lane, acc);
  run_seg<3, 12, 2,  40,  6>(bb, xn, xb, xrd_off, t0, lane, acc);
  run_seg<2, 12, 3,  64,  6>(bb, xn, xb, xrd_off, t0, lane, acc);
  run_seg<1, 12, 4, 100, 12>(bb, xn, xb, xrd_off, t0, lane, acc);
  run_seg<1,  9, 1, 148,  9>(bb, xn, xb, xrd_off, t0, lane, acc);

  // epilogue: D col=lane&15 -> filter-in-tile, row=4q+reg -> t offset
  #pragma unroll
  for (int n = 0; n < 8; ++n) {
    const int F = 16 * n + m;
    const float sc = scale[F];
    #pragma unroll
    for (int mt = 0; mt < MT; ++mt) {
      v4f o = acc[mt][n] * sc;
      *(v4f*)(out + (size_t)(bc * NF + F) * T_OUT + t0 + 16 * mt + 4 * q) = o;
    }
  }
}

extern "C" void kernel_launch(void* const* d_in, const int* in_sizes, int n_in,
                              void* d_out, int out_size, void* d_ws, size_t ws_size,
                              hipStream_t stream) {
  const float* noise = (const float*)d_in[0];   // (2, 8, 9095) fp32
  const float* filt  = (const float*)d_in[1];   // (128, 5000) fp32
  const float* scale = (const float*)d_in[2];   // (1, 128, 1) fp32
  float* out = (float*)d_out;                   // (2, 1024, 4096) fp32

  unsigned short* swz = (unsigned short*)d_ws;              // 1.44 MB
  float* xpad = (float*)((char*)d_ws + SWZ_BYTES);          // 16 x 9344 fp32

  const int pad_blocks = (NBC * XPS + 255) / 256;           // 584
  build_pre<<<314 + pad_blocks, 256, 0, stream>>>(filt, noise, swz, xpad);
  blur_mfma<<<2048, 64, 0, stream>>>(xpad, swz, scale, out);
}